// Round 9
// baseline (945.796 us; speedup 1.0000x reference)
//
#include <hip/hip_runtime.h>
#include <hip/hip_bf16.h>

typedef __hip_bfloat16 bf16;
typedef unsigned short ush;
typedef __attribute__((ext_vector_type(8))) unsigned short ush8;
typedef __attribute__((ext_vector_type(4))) float f4;

#define IN_CH 32
#define HID 128
#define OUT_CH 32
#define WPAD 34              // padded leading dim for W1 tiles in LDS (ush)
#define WOFF (HID * WPAD)    // offset of W1r block

__device__ __forceinline__ float bf2f(ush u) {
    return __uint_as_float(((unsigned)u) << 16);
}
__device__ __forceinline__ ush f2bf(float f) {
    __hip_bfloat16 b = __float2bfloat16(f);
    return __builtin_bit_cast(ush, b);
}
__device__ __forceinline__ float ldf(const void* __restrict__ p, size_t idx, int isbf16) {
    return isbf16 ? bf2f(((const ush*)p)[idx]) : ((const float*)p)[idx];
}
__device__ __forceinline__ int ld_edge(const int* __restrict__ ei, size_t elem, int wide) {
    return wide ? ei[2 * elem] : ei[elem];
}

// ---------- sniff dtypes: flags[0]=float_is_bf16, flags[1]=edge_is_i64 ----------
__global__ void k_detect(const unsigned short* __restrict__ xraw,
                         const int* __restrict__ ei, int* __restrict__ flags) {
    __shared__ int cnt_exp, any_nz;
    if (threadIdx.x == 0) { cnt_exp = 0; any_nz = 0; }
    __syncthreads();
    int local = 0;
    for (int k = threadIdx.x; k < 4096; k += 256) {
        int e = (xraw[k] >> 7) & 0xFF;
        if (e >= 100 && e <= 140) ++local;
    }
    atomicAdd(&cnt_exp, local);
    for (int k = threadIdx.x; k < 2048; k += 256)
        if (ei[2 * k + 1] != 0) any_nz = 1;   // benign race
    __syncthreads();
    if (threadIdx.x == 0) {
        flags[0] = (cnt_exp > 3500) ? 1 : 0;
        flags[1] = any_nz ? 0 : 1;
    }
}

__global__ void k_count(const int* __restrict__ ei, int n_edges,
                        const int* __restrict__ flags, int* __restrict__ cnt) {
    int e = blockIdx.x * blockDim.x + threadIdx.x;
    if (e >= n_edges) return;
    int w = flags[1];
    atomicAdd(&cnt[ld_edge(ei, (size_t)n_edges + e, w)], 1);
}

// ---------- scan-free CSR region allocation (one atomic per wave) ----------
__global__ __launch_bounds__(256) void k_alloc(const int* __restrict__ cnt, int n,
                                               int* __restrict__ start,
                                               int* __restrict__ cursor,
                                               int* __restrict__ total) {
    int i = blockIdx.x * blockDim.x + threadIdx.x;
    int lane = threadIdx.x & 63;
    int d = (i < n) ? cnt[i] : 0;
    int p = d;
#pragma unroll
    for (int off = 1; off < 64; off <<= 1) {
        int v = __shfl_up(p, off);
        if (lane >= off) p += v;
    }
    int wtot = __shfl(p, 63);
    int base = 0;
    if (lane == 63) base = atomicAdd(total, wtot);
    base = __shfl(base, 63);
    int s = base + p - d;
    if (i < n) { start[i] = s; cursor[i] = s; }
}

__global__ void k_fill(const int* __restrict__ ei, int n_edges,
                       const int* __restrict__ flags,
                       int* __restrict__ cursor, int* __restrict__ csr) {
    int e = blockIdx.x * blockDim.x + threadIdx.x;
    if (e >= n_edges) return;
    int w = flags[1];
    int d = ld_edge(ei, (size_t)n_edges + e, w);
    int s = ld_edge(ei, (size_t)e, w);
    int p = atomicAdd(&cursor[d], 1);
    csr[p] = s;
}

// ==== layer 1: h[i] = relu(mean_j x[j] @ W1l^T + x[i] @ W1r^T + b1), 32 -> 128 ====
// wave-per-node; lane = (slot 0..15 = edge slot, chunk 0..3 = 8-channel chunk).
// Weights live in LDS (padded stride) — epilogue reads them per node, keeping
// persistent VGPR <= 64 so 8 waves/SIMD are resident (occupancy is the limiter).
__global__ __launch_bounds__(256, 8) void k_l1(
        const void* __restrict__ x,
        const int* __restrict__ start, const int* __restrict__ cnt,
        const int* __restrict__ csr,
        const void* __restrict__ W1l, const void* __restrict__ W1r,
        const void* __restrict__ b1,
        const int* __restrict__ flags,
        ush* __restrict__ hout, int n_nodes, int n_edges) {
    __shared__ ush wst[2 * WOFF];     // W1l then W1r, [o][c] stride WPAD, ~17 KB
    __shared__ float bs[HID];
    int fb = flags[0];
    int t = threadIdx.x;
    for (int idx = t; idx < HID * IN_CH; idx += 256) {
        int o = idx >> 5, c = idx & 31;
        wst[o * WPAD + c]        = f2bf(ldf(W1l, idx, fb));
        wst[WOFF + o * WPAD + c] = f2bf(ldf(W1r, idx, fb));
    }
    if (t < HID) bs[t] = ldf(b1, t, fb);
    __syncthreads();
    int wave = t >> 6, lane = t & 63;
    int slot = lane >> 2;    // 0..15
    int chunk = lane & 3;    // 0..3
    int gw = blockIdx.x * 4 + wave;
    int nw = gridDim.x * 4;
    for (int i = gw; i < n_nodes; i += nw) {
        int beg = start[i], dg = cnt[i], end = beg + dg;
        float acc[8] = {0, 0, 0, 0, 0, 0, 0, 0};
        float sv[8];
        if (fb) {
            const ush* xb = (const ush*)x;
            for (int base = beg; base < end; base += 64) {
                int idxv = csr[min(base + lane, n_edges - 1)];
                int lim = min(64, end - base);
                for (int g = 0; g < lim; g += 16) {
                    int k = g + slot;
                    int src = __shfl(idxv, k);
                    bool ok = k < lim;
                    ush8 v = *(const ush8*)(xb + (size_t)(ok ? src : i) * IN_CH + chunk * 8);
#pragma unroll
                    for (int j = 0; j < 8; ++j) acc[j] += ok ? bf2f(v[j]) : 0.0f;
                }
            }
            ush8 svv = *(const ush8*)(xb + (size_t)i * IN_CH + chunk * 8);
#pragma unroll
            for (int j = 0; j < 8; ++j) sv[j] = bf2f(svv[j]);
        } else {
            const float* xb = (const float*)x;
            for (int base = beg; base < end; base += 64) {
                int idxv = csr[min(base + lane, n_edges - 1)];
                int lim = min(64, end - base);
                for (int g = 0; g < lim; g += 16) {
                    int k = g + slot;
                    int src = __shfl(idxv, k);
                    bool ok = k < lim;
                    const float* rp = xb + (size_t)(ok ? src : i) * IN_CH + chunk * 8;
                    f4 a0 = *(const f4*)rp;
                    f4 a1 = *(const f4*)(rp + 4);
#pragma unroll
                    for (int j = 0; j < 4; ++j) {
                        acc[j]     += ok ? a0[j] : 0.0f;
                        acc[4 + j] += ok ? a1[j] : 0.0f;
                    }
                }
            }
            const float* rp = xb + (size_t)i * IN_CH + chunk * 8;
            f4 a0 = *(const f4*)rp;
            f4 a1 = *(const f4*)(rp + 4);
#pragma unroll
            for (int j = 0; j < 4; ++j) { sv[j] = a0[j]; sv[4 + j] = a1[j]; }
        }
#pragma unroll
        for (int j = 0; j < 8; ++j) {
            acc[j] += __shfl_xor(acc[j], 4);
            acc[j] += __shfl_xor(acc[j], 8);
            acc[j] += __shfl_xor(acc[j], 16);
            acc[j] += __shfl_xor(acc[j], 32);
        }
        float rdeg = 1.0f / (float)(dg > 1 ? dg : 1);
#pragma unroll
        for (int j = 0; j < 8; ++j) acc[j] *= rdeg;   // acc = mean now
        float po[8];
#pragma unroll
        for (int j = 0; j < 8; ++j) {
            int o = slot * 8 + j;
            ush8 wl = *(const ush8*)&wst[o * WPAD + chunk * 8];
            ush8 wr = *(const ush8*)&wst[WOFF + o * WPAD + chunk * 8];
            float s = 0.0f;
#pragma unroll
            for (int c = 0; c < 8; ++c)
                s += acc[c] * bf2f(wl[c]) + sv[c] * bf2f(wr[c]);
            po[j] = s;
        }
#pragma unroll
        for (int j = 0; j < 8; ++j) {
            po[j] += __shfl_xor(po[j], 1);
            po[j] += __shfl_xor(po[j], 2);
        }
        if (chunk == 0) {
            ush8 ov;
#pragma unroll
            for (int j = 0; j < 8; ++j) {
                float v = po[j] + bs[slot * 8 + j];
                ov[j] = f2bf(v > 0.0f ? v : 0.0f);
            }
            *(ush8*)(hout + (size_t)i * HID + slot * 8) = ov;
        }
    }
}

// ==== g = h @ W2l^T (bf16), s = h @ W2r^T + b2 (bf16) — dense, per node ====
__global__ __launch_bounds__(256) void k_g(
        const ush* __restrict__ h,
        const void* __restrict__ W2l, const void* __restrict__ W2r,
        const void* __restrict__ b2,
        const int* __restrict__ flags,
        ush* __restrict__ g, ush* __restrict__ s, int n_nodes) {
    __shared__ ush wst[2 * OUT_CH * HID];  // 16 KB
    int fb = flags[0];
    int t = threadIdx.x;
    for (int idx = t; idx < OUT_CH * HID; idx += 256) {
        wst[idx]                  = f2bf(ldf(W2l, idx, fb));
        wst[OUT_CH * HID + idx]   = f2bf(ldf(W2r, idx, fb));
    }
    __syncthreads();
    int wave = t >> 6, lane = t & 63;
    int slot = lane >> 4;    // 0..3
    int chunk = lane & 15;   // 0..15
    ush8 wlr[8], wrr[8];
    float bsr[8];
#pragma unroll
    for (int j = 0; j < 8; ++j) {
        int o = slot * 8 + j;
        wlr[j] = *(const ush8*)&wst[o * HID + chunk * 8];
        wrr[j] = *(const ush8*)&wst[OUT_CH * HID + o * HID + chunk * 8];
        bsr[j] = ldf(b2, o, fb);
    }
    int gw = blockIdx.x * 4 + wave;
    int nw = gridDim.x * 4;
    for (int i = gw; i < n_nodes; i += nw) {
        ush8 hv = *(const ush8*)(h + (size_t)i * HID + chunk * 8);
        float sv[8];
#pragma unroll
        for (int j = 0; j < 8; ++j) sv[j] = bf2f(hv[j]);
        float pg[8], ps[8];
#pragma unroll
        for (int j = 0; j < 8; ++j) {
            float a = 0.0f, b = 0.0f;
#pragma unroll
            for (int c = 0; c < 8; ++c) {
                a += sv[c] * bf2f(wlr[j][c]);
                b += sv[c] * bf2f(wrr[j][c]);
            }
            pg[j] = a; ps[j] = b;
        }
#pragma unroll
        for (int j = 0; j < 8; ++j) {
            pg[j] += __shfl_xor(pg[j], 1);
            pg[j] += __shfl_xor(pg[j], 2);
            pg[j] += __shfl_xor(pg[j], 4);
            pg[j] += __shfl_xor(pg[j], 8);
            ps[j] += __shfl_xor(ps[j], 1);
            ps[j] += __shfl_xor(ps[j], 2);
            ps[j] += __shfl_xor(ps[j], 4);
            ps[j] += __shfl_xor(ps[j], 8);
        }
        if (chunk == 0) {
            ush8 go, so;
#pragma unroll
            for (int j = 0; j < 8; ++j) {
                go[j] = f2bf(pg[j]);
                so[j] = f2bf(ps[j] + bsr[j]);
            }
            *(ush8*)(g + (size_t)i * OUT_CH + slot * 8) = go;
            *(ush8*)(s + (size_t)i * OUT_CH + slot * 8) = so;
        }
    }
}

// ==== out[i] = mean_j g[j] + s[i] — 64B-row gather, minimal VGPR ====
// wave-per-node; lane = (slot 0..15 = edge slot, chunk 0..3 = 8-channel chunk)
__global__ __launch_bounds__(256, 8) void k_l2g(
        const ush* __restrict__ g, const ush* __restrict__ s,
        const int* __restrict__ start, const int* __restrict__ cnt,
        const int* __restrict__ csr,
        const int* __restrict__ flags,
        void* __restrict__ out, int n_nodes, int n_edges) {
    int fb = flags[0];
    int t = threadIdx.x;
    int wave = t >> 6, lane = t & 63;
    int slot = lane >> 2;    // 0..15
    int chunk = lane & 3;    // 0..3
    int gw = blockIdx.x * 4 + wave;
    int nw = gridDim.x * 4;
    for (int i = gw; i < n_nodes; i += nw) {
        int beg = start[i], dg = cnt[i], end = beg + dg;
        float acc[8] = {0, 0, 0, 0, 0, 0, 0, 0};
        for (int base = beg; base < end; base += 64) {
            int idxv = csr[min(base + lane, n_edges - 1)];
            int lim = min(64, end - base);
            for (int gg = 0; gg < lim; gg += 16) {
                int k = gg + slot;
                int src = __shfl(idxv, k);
                bool ok = k < lim;
                ush8 v = *(const ush8*)(g + (size_t)(ok ? src : i) * OUT_CH + chunk * 8);
#pragma unroll
                for (int j = 0; j < 8; ++j) acc[j] += ok ? bf2f(v[j]) : 0.0f;
            }
        }
#pragma unroll
        for (int j = 0; j < 8; ++j) {
            acc[j] += __shfl_xor(acc[j], 4);
            acc[j] += __shfl_xor(acc[j], 8);
            acc[j] += __shfl_xor(acc[j], 16);
            acc[j] += __shfl_xor(acc[j], 32);
        }
        if (slot == 0) {   // lanes 0..3 hold chunk 0..3
            float rdeg = 1.0f / (float)(dg > 1 ? dg : 1);
            ush8 selfv = *(const ush8*)(s + (size_t)i * OUT_CH + chunk * 8);
            if (fb) {
                ush8 ov;
#pragma unroll
                for (int j = 0; j < 8; ++j)
                    ov[j] = f2bf(acc[j] * rdeg + bf2f(selfv[j]));
                *(ush8*)((ush*)out + (size_t)i * OUT_CH + chunk * 8) = ov;
            } else {
                float* op = (float*)out + (size_t)i * OUT_CH + chunk * 8;
                f4 a0, a1;
#pragma unroll
                for (int j = 0; j < 4; ++j) {
                    a0[j] = acc[j] * rdeg + bf2f(selfv[j]);
                    a1[j] = acc[4 + j] * rdeg + bf2f(selfv[4 + j]);
                }
                *(f4*)op = a0;
                *(f4*)(op + 4) = a1;
            }
        }
    }
}

extern "C" void kernel_launch(void* const* d_in, const int* in_sizes, int n_in,
                              void* d_out, int out_size, void* d_ws, size_t ws_size,
                              hipStream_t stream) {
    const void* x   = d_in[0];
    const int*  ei  = (const int*)d_in[1];
    const void* W1l = d_in[2];
    const void* W1r = d_in[3];
    const void* b1  = d_in[4];
    const void* W2l = d_in[5];
    const void* W2r = d_in[6];
    const void* b2  = d_in[7];

    int n_nodes = in_sizes[0] / IN_CH;
    int n_edges = in_sizes[1] / 2;

    // ws layout (~46 MB):
    //   [0,256)   flags (2 ints) + total counter (at +128)
    //   cnt (N) | start (N) | cursor (N) | csr (E) | h (N*HID bf16)
    //   | g (N*OUT bf16) | s (N*OUT bf16)
    char* ws = (char*)d_ws;
    size_t o_cnt   = 256;
    size_t o_start = (o_cnt   + (size_t)n_nodes * 4 + 127) & ~(size_t)127;
    size_t o_cur   = (o_start + (size_t)n_nodes * 4 + 127) & ~(size_t)127;
    size_t o_csr   = (o_cur   + (size_t)n_nodes * 4 + 127) & ~(size_t)127;
    size_t o_h     = (o_csr   + (size_t)n_edges * 4 + 255) & ~(size_t)255;
    size_t o_g     = (o_h     + (size_t)n_nodes * HID * 2 + 255) & ~(size_t)255;
    size_t o_s     = (o_g     + (size_t)n_nodes * OUT_CH * 2 + 255) & ~(size_t)255;

    int* flags  = (int*)ws;
    int* total  = (int*)(ws + 128);
    int* cnt    = (int*)(ws + o_cnt);
    int* start  = (int*)(ws + o_start);
    int* cursor = (int*)(ws + o_cur);
    int* csr    = (int*)(ws + o_csr);
    ush* h      = (ush*)(ws + o_h);
    ush* g      = (ush*)(ws + o_g);
    ush* s      = (ush*)(ws + o_s);

    hipMemsetAsync(ws, 0, 256, stream);                          // flags + total
    hipMemsetAsync(cnt, 0, (size_t)n_nodes * 4, stream);

    k_detect<<<1, 256, 0, stream>>>((const unsigned short*)x, ei, flags);
    k_count<<<(n_edges + 255) / 256, 256, 0, stream>>>(ei, n_edges, flags, cnt);
    k_alloc<<<(n_nodes + 255) / 256, 256, 0, stream>>>(cnt, n_nodes, start, cursor, total);
    k_fill<<<(n_edges + 255) / 256, 256, 0, stream>>>(ei, n_edges, flags, cursor, csr);

    k_l1<<<2048, 256, 0, stream>>>(x, start, cnt, csr, W1l, W1r, b1, flags, h, n_nodes, n_edges);
    k_g<<<512, 256, 0, stream>>>(h, W2l, W2r, b2, flags, g, s, n_nodes);
    k_l2g<<<2048, 256, 0, stream>>>(g, s, start, cnt, csr, flags, d_out, n_nodes, n_edges);
}

// Round 10
// 670.762 us; speedup vs baseline: 1.4100x; 1.4100x over previous
//
#include <hip/hip_runtime.h>
#include <hip/hip_bf16.h>

typedef __hip_bfloat16 bf16;
typedef unsigned short ush;
typedef __attribute__((ext_vector_type(8))) unsigned short ush8;
typedef __attribute__((ext_vector_type(4))) float f4;

#define IN_CH 32
#define HID 128
#define OUT_CH 32

__device__ __forceinline__ float bf2f(ush u) {
    return __uint_as_float(((unsigned)u) << 16);
}
__device__ __forceinline__ ush f2bf(float f) {
    __hip_bfloat16 b = __float2bfloat16(f);
    return __builtin_bit_cast(ush, b);
}
__device__ __forceinline__ float ldf(const void* __restrict__ p, size_t idx, int isbf16) {
    return isbf16 ? bf2f(((const ush*)p)[idx]) : ((const float*)p)[idx];
}
__device__ __forceinline__ int ld_edge(const int* __restrict__ ei, size_t elem, int wide) {
    return wide ? ei[2 * elem] : ei[elem];
}

// ---------- sniff dtypes: flags[0]=float_is_bf16, flags[1]=edge_is_i64 ----------
__global__ void k_detect(const unsigned short* __restrict__ xraw,
                         const int* __restrict__ ei, int* __restrict__ flags) {
    __shared__ int cnt_exp, any_nz;
    if (threadIdx.x == 0) { cnt_exp = 0; any_nz = 0; }
    __syncthreads();
    int local = 0;
    for (int k = threadIdx.x; k < 4096; k += 256) {
        int e = (xraw[k] >> 7) & 0xFF;
        if (e >= 100 && e <= 140) ++local;
    }
    atomicAdd(&cnt_exp, local);
    for (int k = threadIdx.x; k < 2048; k += 256)
        if (ei[2 * k + 1] != 0) any_nz = 1;   // benign race
    __syncthreads();
    if (threadIdx.x == 0) {
        flags[0] = (cnt_exp > 3500) ? 1 : 0;
        flags[1] = any_nz ? 0 : 1;
    }
}

__global__ void k_count(const int* __restrict__ ei, int n_edges,
                        const int* __restrict__ flags, int* __restrict__ cnt) {
    int e = blockIdx.x * blockDim.x + threadIdx.x;
    if (e >= n_edges) return;
    int w = flags[1];
    atomicAdd(&cnt[ld_edge(ei, (size_t)n_edges + e, w)], 1);
}

// ---------- scan-free CSR region allocation (one atomic per wave) ----------
__global__ __launch_bounds__(256) void k_alloc(const int* __restrict__ cnt, int n,
                                               int* __restrict__ start,
                                               int* __restrict__ cursor,
                                               int* __restrict__ total) {
    int i = blockIdx.x * blockDim.x + threadIdx.x;
    int lane = threadIdx.x & 63;
    int d = (i < n) ? cnt[i] : 0;
    int p = d;
#pragma unroll
    for (int off = 1; off < 64; off <<= 1) {
        int v = __shfl_up(p, off);
        if (lane >= off) p += v;
    }
    int wtot = __shfl(p, 63);
    int base = 0;
    if (lane == 63) base = atomicAdd(total, wtot);
    base = __shfl(base, 63);
    int s = base + p - d;
    if (i < n) { start[i] = s; cursor[i] = s; }
}

__global__ void k_fill(const int* __restrict__ ei, int n_edges,
                       const int* __restrict__ flags,
                       int* __restrict__ cursor, int* __restrict__ csr) {
    int e = blockIdx.x * blockDim.x + threadIdx.x;
    if (e >= n_edges) return;
    int w = flags[1];
    int d = ld_edge(ei, (size_t)n_edges + e, w);
    int s = ld_edge(ei, (size_t)e, w);
    int p = atomicAdd(&cursor[d], 1);
    csr[p] = s;
}

// ==== layer 1: h[i] = relu(mean_j x[j] @ W1l^T + x[i] @ W1r^T + b1), 32 -> 128 ====
// wave-per-node; lane = (slot 0..15 = edge slot, chunk 0..3 = 8-channel chunk).
// Cross-iteration software pipeline: next node's start/cnt/csr loads issue
// while the current node's gather+GEMV executes (hides the index-chain).
__global__ __launch_bounds__(256) void k_l1(
        const void* __restrict__ x,
        const int* __restrict__ start, const int* __restrict__ cnt,
        const int* __restrict__ csr,
        const void* __restrict__ W1l, const void* __restrict__ W1r,
        const void* __restrict__ b1,
        const int* __restrict__ flags,
        ush* __restrict__ hout, int n_nodes, int n_edges) {
    __shared__ ush wst[2 * HID * IN_CH];   // 16 KB: W1l then W1r, bf16 [o][c]
    int fb = flags[0];
    int t = threadIdx.x;
    for (int idx = t; idx < HID * IN_CH; idx += 256) {
        wst[idx]                 = f2bf(ldf(W1l, idx, fb));
        wst[HID * IN_CH + idx]   = f2bf(ldf(W1r, idx, fb));
    }
    __syncthreads();
    int wave = t >> 6, lane = t & 63;
    int slot = lane >> 2;    // 0..15
    int chunk = lane & 3;    // 0..3
    ush8 wlr[8], wrr[8];
    float bsr[8];
#pragma unroll
    for (int j = 0; j < 8; ++j) {
        int o = slot * 8 + j;
        wlr[j] = *(const ush8*)&wst[o * IN_CH + chunk * 8];
        wrr[j] = *(const ush8*)&wst[HID * IN_CH + o * IN_CH + chunk * 8];
        bsr[j] = ldf(b1, o, fb);
    }
    int gw = blockIdx.x * 4 + wave;
    int nw = gridDim.x * 4;
    if (fb) {
        // ---- hot path: bf16, pipelined ----
        const ush* xb = (const ush*)x;
        int i = gw;
        int beg = 0, dg = 0, idxv = 0;
        if (i < n_nodes) {
            beg = start[i]; dg = cnt[i];
            idxv = csr[min(beg + lane, n_edges - 1)];
        }
        while (i < n_nodes) {
            int inext = i + nw;
            int beg_n = 0, dg_n = 0, idx_n = 0;
            if (inext < n_nodes) {                 // prefetch next node (chain hidden)
                beg_n = start[inext]; dg_n = cnt[inext];
                idx_n = csr[min(beg_n + lane, n_edges - 1)];
            }
            ush8 svv = *(const ush8*)(xb + (size_t)i * IN_CH + chunk * 8);
            float acc[8] = {0, 0, 0, 0, 0, 0, 0, 0};
            {   // first 64-edge chunk uses preloaded idxv (common case: deg<=64)
                int lim = min(64, dg);
                for (int g = 0; g < lim; g += 16) {
                    int k = g + slot;
                    int src = __shfl(idxv, k);
                    bool ok = k < lim;
                    ush8 v = *(const ush8*)(xb + (size_t)(ok ? src : i) * IN_CH + chunk * 8);
#pragma unroll
                    for (int j = 0; j < 8; ++j) acc[j] += ok ? bf2f(v[j]) : 0.0f;
                }
            }
            for (int base = 64; base < dg; base += 64) {   // rare tail
                int idxv2 = csr[min(beg + base + lane, n_edges - 1)];
                int lim = min(64, dg - base);
                for (int g = 0; g < lim; g += 16) {
                    int k = g + slot;
                    int src = __shfl(idxv2, k);
                    bool ok = k < lim;
                    ush8 v = *(const ush8*)(xb + (size_t)(ok ? src : i) * IN_CH + chunk * 8);
#pragma unroll
                    for (int j = 0; j < 8; ++j) acc[j] += ok ? bf2f(v[j]) : 0.0f;
                }
            }
#pragma unroll
            for (int j = 0; j < 8; ++j) {
                acc[j] += __shfl_xor(acc[j], 4);
                acc[j] += __shfl_xor(acc[j], 8);
                acc[j] += __shfl_xor(acc[j], 16);
                acc[j] += __shfl_xor(acc[j], 32);
            }
            float rdeg = 1.0f / (float)(dg > 1 ? dg : 1);
#pragma unroll
            for (int j = 0; j < 8; ++j) acc[j] *= rdeg;
            float po[8];
#pragma unroll
            for (int j = 0; j < 8; ++j) {
                float s = 0.0f;
#pragma unroll
                for (int c = 0; c < 8; ++c)
                    s += acc[c] * bf2f(wlr[j][c]) + bf2f(svv[c]) * bf2f(wrr[j][c]);
                po[j] = s;
            }
#pragma unroll
            for (int j = 0; j < 8; ++j) {
                po[j] += __shfl_xor(po[j], 1);
                po[j] += __shfl_xor(po[j], 2);
            }
            if (chunk == 0) {
                ush8 ov;
#pragma unroll
                for (int j = 0; j < 8; ++j) {
                    float v = po[j] + bsr[j];
                    ov[j] = f2bf(v > 0.0f ? v : 0.0f);
                }
                *(ush8*)(hout + (size_t)i * HID + slot * 8) = ov;
            }
            i = inext; beg = beg_n; dg = dg_n; idxv = idx_n;
        }
    } else {
        // ---- cold path: f32 input (round-7 code) ----
        const float* xb = (const float*)x;
        for (int i = gw; i < n_nodes; i += nw) {
            int beg = start[i], dg = cnt[i], end = beg + dg;
            float acc[8] = {0,0,0,0,0,0,0,0};
            for (int base = beg; base < end; base += 64) {
                int idxv = csr[min(base + lane, n_edges - 1)];
                int lim = min(64, end - base);
                for (int g = 0; g < lim; g += 16) {
                    int k = g + slot;
                    int src = __shfl(idxv, k);
                    bool ok = k < lim;
                    const float* rp = xb + (size_t)(ok ? src : i) * IN_CH + chunk * 8;
                    f4 a0 = *(const f4*)rp;
                    f4 a1 = *(const f4*)(rp + 4);
#pragma unroll
                    for (int j = 0; j < 4; ++j) {
                        acc[j]     += ok ? a0[j] : 0.0f;
                        acc[4 + j] += ok ? a1[j] : 0.0f;
                    }
                }
            }
#pragma unroll
            for (int j = 0; j < 8; ++j) {
                acc[j] += __shfl_xor(acc[j], 4);
                acc[j] += __shfl_xor(acc[j], 8);
                acc[j] += __shfl_xor(acc[j], 16);
                acc[j] += __shfl_xor(acc[j], 32);
            }
            float rdeg = 1.0f / (float)(dg > 1 ? dg : 1);
            float sv[8];
            const float* rp = xb + (size_t)i * IN_CH + chunk * 8;
            f4 a0 = *(const f4*)rp;
            f4 a1 = *(const f4*)(rp + 4);
#pragma unroll
            for (int j = 0; j < 4; ++j) { sv[j] = a0[j]; sv[4 + j] = a1[j]; }
            float po[8];
#pragma unroll
            for (int j = 0; j < 8; ++j) {
                float s = 0.0f;
#pragma unroll
                for (int c = 0; c < 8; ++c)
                    s += (acc[c] * rdeg) * bf2f(wlr[j][c]) + sv[c] * bf2f(wrr[j][c]);
                po[j] = s;
            }
#pragma unroll
            for (int j = 0; j < 8; ++j) {
                po[j] += __shfl_xor(po[j], 1);
                po[j] += __shfl_xor(po[j], 2);
            }
            if (chunk == 0) {
                ush8 ov;
#pragma unroll
                for (int j = 0; j < 8; ++j) {
                    float v = po[j] + bsr[j];
                    ov[j] = f2bf(v > 0.0f ? v : 0.0f);
                }
                *(ush8*)(hout + (size_t)i * HID + slot * 8) = ov;
            }
        }
    }
}

// ==== g = h @ W2l^T (bf16), s = h @ W2r^T + b2 (bf16) — dense, per node ====
__global__ __launch_bounds__(256) void k_g(
        const ush* __restrict__ h,
        const void* __restrict__ W2l, const void* __restrict__ W2r,
        const void* __restrict__ b2,
        const int* __restrict__ flags,
        ush* __restrict__ g, ush* __restrict__ s, int n_nodes) {
    __shared__ ush wst[2 * OUT_CH * HID];  // 16 KB
    int fb = flags[0];
    int t = threadIdx.x;
    for (int idx = t; idx < OUT_CH * HID; idx += 256) {
        wst[idx]                  = f2bf(ldf(W2l, idx, fb));
        wst[OUT_CH * HID + idx]   = f2bf(ldf(W2r, idx, fb));
    }
    __syncthreads();
    int wave = t >> 6, lane = t & 63;
    int slot = lane >> 4;    // 0..3
    int chunk = lane & 15;   // 0..15
    ush8 wlr[8], wrr[8];
    float bsr[8];
#pragma unroll
    for (int j = 0; j < 8; ++j) {
        int o = slot * 8 + j;
        wlr[j] = *(const ush8*)&wst[o * HID + chunk * 8];
        wrr[j] = *(const ush8*)&wst[OUT_CH * HID + o * HID + chunk * 8];
        bsr[j] = ldf(b2, o, fb);
    }
    int gw = blockIdx.x * 4 + wave;
    int nw = gridDim.x * 4;
    for (int i = gw; i < n_nodes; i += nw) {
        ush8 hv = *(const ush8*)(h + (size_t)i * HID + chunk * 8);
        float sv[8];
#pragma unroll
        for (int j = 0; j < 8; ++j) sv[j] = bf2f(hv[j]);
        float pg[8], ps[8];
#pragma unroll
        for (int j = 0; j < 8; ++j) {
            float a = 0.0f, b = 0.0f;
#pragma unroll
            for (int c = 0; c < 8; ++c) {
                a += sv[c] * bf2f(wlr[j][c]);
                b += sv[c] * bf2f(wrr[j][c]);
            }
            pg[j] = a; ps[j] = b;
        }
#pragma unroll
        for (int j = 0; j < 8; ++j) {
            pg[j] += __shfl_xor(pg[j], 1);
            pg[j] += __shfl_xor(pg[j], 2);
            pg[j] += __shfl_xor(pg[j], 4);
            pg[j] += __shfl_xor(pg[j], 8);
            ps[j] += __shfl_xor(ps[j], 1);
            ps[j] += __shfl_xor(ps[j], 2);
            ps[j] += __shfl_xor(ps[j], 4);
            ps[j] += __shfl_xor(ps[j], 8);
        }
        if (chunk == 0) {
            ush8 go, so;
#pragma unroll
            for (int j = 0; j < 8; ++j) {
                go[j] = f2bf(pg[j]);
                so[j] = f2bf(ps[j] + bsr[j]);
            }
            *(ush8*)(g + (size_t)i * OUT_CH + slot * 8) = go;
            *(ush8*)(s + (size_t)i * OUT_CH + slot * 8) = so;
        }
    }
}

// ==== out[i] = mean_j g[j] + s[i] — 64B-row gather, pipelined ====
// wave-per-node; lane = (slot 0..15 = edge slot, chunk 0..3 = 8-channel chunk)
__global__ __launch_bounds__(256) void k_l2g(
        const ush* __restrict__ g, const ush* __restrict__ s,
        const int* __restrict__ start, const int* __restrict__ cnt,
        const int* __restrict__ csr,
        const int* __restrict__ flags,
        void* __restrict__ out, int n_nodes, int n_edges) {
    int fb = flags[0];
    int t = threadIdx.x;
    int wave = t >> 6, lane = t & 63;
    int slot = lane >> 2;    // 0..15
    int chunk = lane & 3;    // 0..3
    int gw = blockIdx.x * 4 + wave;
    int nw = gridDim.x * 4;
    int i = gw;
    int beg = 0, dg = 0, idxv = 0;
    if (i < n_nodes) {
        beg = start[i]; dg = cnt[i];
        idxv = csr[min(beg + lane, n_edges - 1)];
    }
    while (i < n_nodes) {
        int inext = i + nw;
        int beg_n = 0, dg_n = 0, idx_n = 0;
        if (inext < n_nodes) {                 // prefetch next node
            beg_n = start[inext]; dg_n = cnt[inext];
            idx_n = csr[min(beg_n + lane, n_edges - 1)];
        }
        ush8 selfv = *(const ush8*)(s + (size_t)i * OUT_CH + chunk * 8);
        float acc[8] = {0, 0, 0, 0, 0, 0, 0, 0};
        {
            int lim = min(64, dg);
            for (int gg = 0; gg < lim; gg += 16) {
                int k = gg + slot;
                int src = __shfl(idxv, k);
                bool ok = k < lim;
                ush8 v = *(const ush8*)(g + (size_t)(ok ? src : i) * OUT_CH + chunk * 8);
#pragma unroll
                for (int j = 0; j < 8; ++j) acc[j] += ok ? bf2f(v[j]) : 0.0f;
            }
        }
        for (int base = 64; base < dg; base += 64) {   // rare tail
            int idxv2 = csr[min(beg + base + lane, n_edges - 1)];
            int lim = min(64, dg - base);
            for (int gg = 0; gg < lim; gg += 16) {
                int k = gg + slot;
                int src = __shfl(idxv2, k);
                bool ok = k < lim;
                ush8 v = *(const ush8*)(g + (size_t)(ok ? src : i) * OUT_CH + chunk * 8);
#pragma unroll
                for (int j = 0; j < 8; ++j) acc[j] += ok ? bf2f(v[j]) : 0.0f;
            }
        }
#pragma unroll
        for (int j = 0; j < 8; ++j) {
            acc[j] += __shfl_xor(acc[j], 4);
            acc[j] += __shfl_xor(acc[j], 8);
            acc[j] += __shfl_xor(acc[j], 16);
            acc[j] += __shfl_xor(acc[j], 32);
        }
        if (slot == 0) {   // lanes 0..3 hold chunk 0..3
            float rdeg = 1.0f / (float)(dg > 1 ? dg : 1);
            if (fb) {
                ush8 ov;
#pragma unroll
                for (int j = 0; j < 8; ++j)
                    ov[j] = f2bf(acc[j] * rdeg + bf2f(selfv[j]));
                *(ush8*)((ush*)out + (size_t)i * OUT_CH + chunk * 8) = ov;
            } else {
                float* op = (float*)out + (size_t)i * OUT_CH + chunk * 8;
                f4 a0, a1;
#pragma unroll
                for (int j = 0; j < 4; ++j) {
                    a0[j] = acc[j] * rdeg + bf2f(selfv[j]);
                    a1[j] = acc[4 + j] * rdeg + bf2f(selfv[4 + j]);
                }
                *(f4*)op = a0;
                *(f4*)(op + 4) = a1;
            }
        }
        i = inext; beg = beg_n; dg = dg_n; idxv = idx_n;
    }
}

extern "C" void kernel_launch(void* const* d_in, const int* in_sizes, int n_in,
                              void* d_out, int out_size, void* d_ws, size_t ws_size,
                              hipStream_t stream) {
    const void* x   = d_in[0];
    const int*  ei  = (const int*)d_in[1];
    const void* W1l = d_in[2];
    const void* W1r = d_in[3];
    const void* b1  = d_in[4];
    const void* W2l = d_in[5];
    const void* W2r = d_in[6];
    const void* b2  = d_in[7];

    int n_nodes = in_sizes[0] / IN_CH;
    int n_edges = in_sizes[1] / 2;

    // ws layout (~46 MB):
    //   [0,256)   flags (2 ints) + total counter (at +128)
    //   cnt (N) | start (N) | cursor (N) | csr (E) | h (N*HID bf16)
    //   | g (N*OUT bf16) | s (N*OUT bf16)
    char* ws = (char*)d_ws;
    size_t o_cnt   = 256;
    size_t o_start = (o_cnt   + (size_t)n_nodes * 4 + 127) & ~(size_t)127;
    size_t o_cur   = (o_start + (size_t)n_nodes * 4 + 127) & ~(size_t)127;
    size_t o_csr   = (o_cur   + (size_t)n_nodes * 4 + 127) & ~(size_t)127;
    size_t o_h     = (o_csr   + (size_t)n_edges * 4 + 255) & ~(size_t)255;
    size_t o_g     = (o_h     + (size_t)n_nodes * HID * 2 + 255) & ~(size_t)255;
    size_t o_s     = (o_g     + (size_t)n_nodes * OUT_CH * 2 + 255) & ~(size_t)255;

    int* flags  = (int*)ws;
    int* total  = (int*)(ws + 128);
    int* cnt    = (int*)(ws + o_cnt);
    int* start  = (int*)(ws + o_start);
    int* cursor = (int*)(ws + o_cur);
    int* csr    = (int*)(ws + o_csr);
    ush* h      = (ush*)(ws + o_h);
    ush* g      = (ush*)(ws + o_g);
    ush* s      = (ush*)(ws + o_s);

    hipMemsetAsync(ws, 0, 256, stream);                          // flags + total
    hipMemsetAsync(cnt, 0, (size_t)n_nodes * 4, stream);

    k_detect<<<1, 256, 0, stream>>>((const unsigned short*)x, ei, flags);
    k_count<<<(n_edges + 255) / 256, 256, 0, stream>>>(ei, n_edges, flags, cnt);
    k_alloc<<<(n_nodes + 255) / 256, 256, 0, stream>>>(cnt, n_nodes, start, cursor, total);
    k_fill<<<(n_edges + 255) / 256, 256, 0, stream>>>(ei, n_edges, flags, cursor, csr);

    k_l1<<<1024, 256, 0, stream>>>(x, start, cnt, csr, W1l, W1r, b1, flags, h, n_nodes, n_edges);
    k_g<<<512, 256, 0, stream>>>(h, W2l, W2r, b2, flags, g, s, n_nodes);
    k_l2g<<<1024, 256, 0, stream>>>(g, s, start, cnt, csr, flags, d_out, n_nodes, n_edges);
}

// Round 11
// 594.955 us; speedup vs baseline: 1.5897x; 1.1274x over previous
//
#include <hip/hip_runtime.h>
#include <hip/hip_bf16.h>

typedef __hip_bfloat16 bf16;
typedef unsigned short ush;
typedef __attribute__((ext_vector_type(8))) unsigned short ush8;
typedef __attribute__((ext_vector_type(4))) float f4;

#define IN_CH 32
#define HID 128
#define OUT_CH 32
#define WPAD 34              // padded leading dim for W1 tiles in LDS (ush)
#define WOFF (HID * WPAD)    // offset of W1r block

__device__ __forceinline__ float bf2f(ush u) {
    return __uint_as_float(((unsigned)u) << 16);
}
__device__ __forceinline__ ush f2bf(float f) {
    __hip_bfloat16 b = __float2bfloat16(f);
    return __builtin_bit_cast(ush, b);
}
__device__ __forceinline__ float ldf(const void* __restrict__ p, size_t idx, int isbf16) {
    return isbf16 ? bf2f(((const ush*)p)[idx]) : ((const float*)p)[idx];
}
__device__ __forceinline__ int ld_edge(const int* __restrict__ ei, size_t elem, int wide) {
    return wide ? ei[2 * elem] : ei[elem];
}

// ---------- sniff dtypes: flags[0]=float_is_bf16, flags[1]=edge_is_i64 ----------
__global__ void k_detect(const unsigned short* __restrict__ xraw,
                         const int* __restrict__ ei, int* __restrict__ flags) {
    __shared__ int cnt_exp, any_nz;
    if (threadIdx.x == 0) { cnt_exp = 0; any_nz = 0; }
    __syncthreads();
    int local = 0;
    for (int k = threadIdx.x; k < 4096; k += 256) {
        int e = (xraw[k] >> 7) & 0xFF;
        if (e >= 100 && e <= 140) ++local;
    }
    atomicAdd(&cnt_exp, local);
    for (int k = threadIdx.x; k < 2048; k += 256)
        if (ei[2 * k + 1] != 0) any_nz = 1;   // benign race
    __syncthreads();
    if (threadIdx.x == 0) {
        flags[0] = (cnt_exp > 3500) ? 1 : 0;
        flags[1] = any_nz ? 0 : 1;
    }
}

__global__ void k_count(const int* __restrict__ ei, int n_edges,
                        const int* __restrict__ flags, int* __restrict__ cnt) {
    int e = blockIdx.x * blockDim.x + threadIdx.x;
    if (e >= n_edges) return;
    int w = flags[1];
    atomicAdd(&cnt[ld_edge(ei, (size_t)n_edges + e, w)], 1);
}

// ---------- scan-free CSR region allocation (one atomic per wave) ----------
__global__ __launch_bounds__(256) void k_alloc(const int* __restrict__ cnt, int n,
                                               int* __restrict__ start,
                                               int* __restrict__ cursor,
                                               int* __restrict__ total) {
    int i = blockIdx.x * blockDim.x + threadIdx.x;
    int lane = threadIdx.x & 63;
    int d = (i < n) ? cnt[i] : 0;
    int p = d;
#pragma unroll
    for (int off = 1; off < 64; off <<= 1) {
        int v = __shfl_up(p, off);
        if (lane >= off) p += v;
    }
    int wtot = __shfl(p, 63);
    int base = 0;
    if (lane == 63) base = atomicAdd(total, wtot);
    base = __shfl(base, 63);
    int s = base + p - d;
    if (i < n) { start[i] = s; cursor[i] = s; }
}

__global__ void k_fill(const int* __restrict__ ei, int n_edges,
                       const int* __restrict__ flags,
                       int* __restrict__ cursor, int* __restrict__ csr) {
    int e = blockIdx.x * blockDim.x + threadIdx.x;
    if (e >= n_edges) return;
    int w = flags[1];
    int d = ld_edge(ei, (size_t)n_edges + e, w);
    int s = ld_edge(ei, (size_t)e, w);
    int p = atomicAdd(&cursor[d], 1);
    csr[p] = s;
}

// ==== layer 1: h[i] = relu(mean_j x[j] @ W1l^T + x[i] @ W1r^T + b1), 32 -> 128 ====
// wave-per-node; lane = (slot 0..15 = edge slot, chunk 0..3 = 8-channel chunk).
// Weights live in LDS (padded stride); NO min-wave force — natural VGPR ~48-64
// gives 6-8 waves/SIMD without spilling (round 9's (256,8) forced 32 -> spills).
__global__ __launch_bounds__(256) void k_l1(
        const void* __restrict__ x,
        const int* __restrict__ start, const int* __restrict__ cnt,
        const int* __restrict__ csr,
        const void* __restrict__ W1l, const void* __restrict__ W1r,
        const void* __restrict__ b1,
        const int* __restrict__ flags,
        ush* __restrict__ hout, int n_nodes, int n_edges) {
    __shared__ ush wst[2 * WOFF];     // W1l then W1r, [o][c] stride WPAD, ~17 KB
    __shared__ float bs[HID];
    int fb = flags[0];
    int t = threadIdx.x;
    for (int idx = t; idx < HID * IN_CH; idx += 256) {
        int o = idx >> 5, c = idx & 31;
        wst[o * WPAD + c]        = f2bf(ldf(W1l, idx, fb));
        wst[WOFF + o * WPAD + c] = f2bf(ldf(W1r, idx, fb));
    }
    if (t < HID) bs[t] = ldf(b1, t, fb);
    __syncthreads();
    int wave = t >> 6, lane = t & 63;
    int slot = lane >> 2;    // 0..15
    int chunk = lane & 3;    // 0..3
    int gw = blockIdx.x * 4 + wave;
    int nw = gridDim.x * 4;
    for (int i = gw; i < n_nodes; i += nw) {
        int beg = start[i], dg = cnt[i], end = beg + dg;
        float acc[8] = {0, 0, 0, 0, 0, 0, 0, 0};
        float sv[8];
        if (fb) {
            const ush* xb = (const ush*)x;
            for (int base = beg; base < end; base += 64) {
                int idxv = csr[min(base + lane, n_edges - 1)];
                int lim = min(64, end - base);
                for (int g = 0; g < lim; g += 16) {
                    int k = g + slot;
                    int src = __shfl(idxv, k);
                    bool ok = k < lim;
                    ush8 v = *(const ush8*)(xb + (size_t)(ok ? src : i) * IN_CH + chunk * 8);
#pragma unroll
                    for (int j = 0; j < 8; ++j) acc[j] += ok ? bf2f(v[j]) : 0.0f;
                }
            }
            ush8 svv = *(const ush8*)(xb + (size_t)i * IN_CH + chunk * 8);
#pragma unroll
            for (int j = 0; j < 8; ++j) sv[j] = bf2f(svv[j]);
        } else {
            const float* xb = (const float*)x;
            for (int base = beg; base < end; base += 64) {
                int idxv = csr[min(base + lane, n_edges - 1)];
                int lim = min(64, end - base);
                for (int g = 0; g < lim; g += 16) {
                    int k = g + slot;
                    int src = __shfl(idxv, k);
                    bool ok = k < lim;
                    const float* rp = xb + (size_t)(ok ? src : i) * IN_CH + chunk * 8;
                    f4 a0 = *(const f4*)rp;
                    f4 a1 = *(const f4*)(rp + 4);
#pragma unroll
                    for (int j = 0; j < 4; ++j) {
                        acc[j]     += ok ? a0[j] : 0.0f;
                        acc[4 + j] += ok ? a1[j] : 0.0f;
                    }
                }
            }
            const float* rp = xb + (size_t)i * IN_CH + chunk * 8;
            f4 a0 = *(const f4*)rp;
            f4 a1 = *(const f4*)(rp + 4);
#pragma unroll
            for (int j = 0; j < 4; ++j) { sv[j] = a0[j]; sv[4 + j] = a1[j]; }
        }
#pragma unroll
        for (int j = 0; j < 8; ++j) {
            acc[j] += __shfl_xor(acc[j], 4);
            acc[j] += __shfl_xor(acc[j], 8);
            acc[j] += __shfl_xor(acc[j], 16);
            acc[j] += __shfl_xor(acc[j], 32);
        }
        float rdeg = 1.0f / (float)(dg > 1 ? dg : 1);
#pragma unroll
        for (int j = 0; j < 8; ++j) acc[j] *= rdeg;   // acc = mean
        float po[8];
#pragma unroll
        for (int j = 0; j < 8; ++j) {
            int o = slot * 8 + j;
            ush8 wl = *(const ush8*)&wst[o * WPAD + chunk * 8];
            ush8 wr = *(const ush8*)&wst[WOFF + o * WPAD + chunk * 8];
            float s = 0.0f;
#pragma unroll
            for (int c = 0; c < 8; ++c)
                s += acc[c] * bf2f(wl[c]) + sv[c] * bf2f(wr[c]);
            po[j] = s;
        }
#pragma unroll
        for (int j = 0; j < 8; ++j) {
            po[j] += __shfl_xor(po[j], 1);
            po[j] += __shfl_xor(po[j], 2);
        }
        if (chunk == 0) {
            ush8 ov;
#pragma unroll
            for (int j = 0; j < 8; ++j) {
                float v = po[j] + bs[slot * 8 + j];
                ov[j] = f2bf(v > 0.0f ? v : 0.0f);
            }
            *(ush8*)(hout + (size_t)i * HID + slot * 8) = ov;
        }
    }
}

// ==== g = h @ W2l^T (bf16), s = h @ W2r^T + b2 (bf16) — dense, per node ====
__global__ __launch_bounds__(256) void k_g(
        const ush* __restrict__ h,
        const void* __restrict__ W2l, const void* __restrict__ W2r,
        const void* __restrict__ b2,
        const int* __restrict__ flags,
        ush* __restrict__ g, ush* __restrict__ s, int n_nodes) {
    __shared__ ush wst[2 * OUT_CH * HID];  // 16 KB
    int fb = flags[0];
    int t = threadIdx.x;
    for (int idx = t; idx < OUT_CH * HID; idx += 256) {
        wst[idx]                  = f2bf(ldf(W2l, idx, fb));
        wst[OUT_CH * HID + idx]   = f2bf(ldf(W2r, idx, fb));
    }
    __syncthreads();
    int wave = t >> 6, lane = t & 63;
    int slot = lane >> 4;    // 0..3
    int chunk = lane & 15;   // 0..15
    ush8 wlr[8], wrr[8];
    float bsr[8];
#pragma unroll
    for (int j = 0; j < 8; ++j) {
        int o = slot * 8 + j;
        wlr[j] = *(const ush8*)&wst[o * HID + chunk * 8];
        wrr[j] = *(const ush8*)&wst[OUT_CH * HID + o * HID + chunk * 8];
        bsr[j] = ldf(b2, o, fb);
    }
    int gw = blockIdx.x * 4 + wave;
    int nw = gridDim.x * 4;
    for (int i = gw; i < n_nodes; i += nw) {
        ush8 hv = *(const ush8*)(h + (size_t)i * HID + chunk * 8);
        float sv[8];
#pragma unroll
        for (int j = 0; j < 8; ++j) sv[j] = bf2f(hv[j]);
        float pg[8], ps[8];
#pragma unroll
        for (int j = 0; j < 8; ++j) {
            float a = 0.0f, b = 0.0f;
#pragma unroll
            for (int c = 0; c < 8; ++c) {
                a += sv[c] * bf2f(wlr[j][c]);
                b += sv[c] * bf2f(wrr[j][c]);
            }
            pg[j] = a; ps[j] = b;
        }
#pragma unroll
        for (int j = 0; j < 8; ++j) {
            pg[j] += __shfl_xor(pg[j], 1);
            pg[j] += __shfl_xor(pg[j], 2);
            pg[j] += __shfl_xor(pg[j], 4);
            pg[j] += __shfl_xor(pg[j], 8);
            ps[j] += __shfl_xor(ps[j], 1);
            ps[j] += __shfl_xor(ps[j], 2);
            ps[j] += __shfl_xor(ps[j], 4);
            ps[j] += __shfl_xor(ps[j], 8);
        }
        if (chunk == 0) {
            ush8 go, so;
#pragma unroll
            for (int j = 0; j < 8; ++j) {
                go[j] = f2bf(pg[j]);
                so[j] = f2bf(ps[j] + bsr[j]);
            }
            *(ush8*)(g + (size_t)i * OUT_CH + slot * 8) = go;
            *(ush8*)(s + (size_t)i * OUT_CH + slot * 8) = so;
        }
    }
}

// ==== out[i] = mean_j g[j] + s[i] — 64B-row gather (round-7 proven body) ====
// wave-per-node; lane = (slot 0..15 = edge slot, chunk 0..3 = 8-channel chunk)
__global__ __launch_bounds__(256) void k_l2g(
        const ush* __restrict__ g, const ush* __restrict__ s,
        const int* __restrict__ start, const int* __restrict__ cnt,
        const int* __restrict__ csr,
        const int* __restrict__ flags,
        void* __restrict__ out, int n_nodes, int n_edges) {
    int fb = flags[0];
    int t = threadIdx.x;
    int wave = t >> 6, lane = t & 63;
    int slot = lane >> 2;    // 0..15
    int chunk = lane & 3;    // 0..3
    int gw = blockIdx.x * 4 + wave;
    int nw = gridDim.x * 4;
    for (int i = gw; i < n_nodes; i += nw) {
        int beg = start[i], dg = cnt[i], end = beg + dg;
        float acc[8] = {0, 0, 0, 0, 0, 0, 0, 0};
        for (int base = beg; base < end; base += 64) {
            int idxv = csr[min(base + lane, n_edges - 1)];
            int lim = min(64, end - base);
            for (int gg = 0; gg < lim; gg += 16) {
                int k = gg + slot;
                int src = __shfl(idxv, k);
                bool ok = k < lim;
                ush8 v = *(const ush8*)(g + (size_t)(ok ? src : i) * OUT_CH + chunk * 8);
#pragma unroll
                for (int j = 0; j < 8; ++j) acc[j] += ok ? bf2f(v[j]) : 0.0f;
            }
        }
#pragma unroll
        for (int j = 0; j < 8; ++j) {
            acc[j] += __shfl_xor(acc[j], 4);
            acc[j] += __shfl_xor(acc[j], 8);
            acc[j] += __shfl_xor(acc[j], 16);
            acc[j] += __shfl_xor(acc[j], 32);
        }
        if (slot == 0) {   // lanes 0..3 hold chunk 0..3
            float rdeg = 1.0f / (float)(dg > 1 ? dg : 1);
            ush8 selfv = *(const ush8*)(s + (size_t)i * OUT_CH + chunk * 8);
            if (fb) {
                ush8 ov;
#pragma unroll
                for (int j = 0; j < 8; ++j)
                    ov[j] = f2bf(acc[j] * rdeg + bf2f(selfv[j]));
                *(ush8*)((ush*)out + (size_t)i * OUT_CH + chunk * 8) = ov;
            } else {
                float* op = (float*)out + (size_t)i * OUT_CH + chunk * 8;
                f4 a0, a1;
#pragma unroll
                for (int j = 0; j < 4; ++j) {
                    a0[j] = acc[j] * rdeg + bf2f(selfv[j]);
                    a1[j] = acc[4 + j] * rdeg + bf2f(selfv[4 + j]);
                }
                *(f4*)op = a0;
                *(f4*)(op + 4) = a1;
            }
        }
    }
}

extern "C" void kernel_launch(void* const* d_in, const int* in_sizes, int n_in,
                              void* d_out, int out_size, void* d_ws, size_t ws_size,
                              hipStream_t stream) {
    const void* x   = d_in[0];
    const int*  ei  = (const int*)d_in[1];
    const void* W1l = d_in[2];
    const void* W1r = d_in[3];
    const void* b1  = d_in[4];
    const void* W2l = d_in[5];
    const void* W2r = d_in[6];
    const void* b2  = d_in[7];

    int n_nodes = in_sizes[0] / IN_CH;
    int n_edges = in_sizes[1] / 2;

    // ws layout (~46 MB):
    //   [0,256)   flags (2 ints) + total counter (at +128)
    //   cnt (N) | start (N) | cursor (N) | csr (E) | h (N*HID bf16)
    //   | g (N*OUT bf16) | s (N*OUT bf16)
    char* ws = (char*)d_ws;
    size_t o_cnt   = 256;
    size_t o_start = (o_cnt   + (size_t)n_nodes * 4 + 127) & ~(size_t)127;
    size_t o_cur   = (o_start + (size_t)n_nodes * 4 + 127) & ~(size_t)127;
    size_t o_csr   = (o_cur   + (size_t)n_nodes * 4 + 127) & ~(size_t)127;
    size_t o_h     = (o_csr   + (size_t)n_edges * 4 + 255) & ~(size_t)255;
    size_t o_g     = (o_h     + (size_t)n_nodes * HID * 2 + 255) & ~(size_t)255;
    size_t o_s     = (o_g     + (size_t)n_nodes * OUT_CH * 2 + 255) & ~(size_t)255;

    int* flags  = (int*)ws;
    int* total  = (int*)(ws + 128);
    int* cnt    = (int*)(ws + o_cnt);
    int* start  = (int*)(ws + o_start);
    int* cursor = (int*)(ws + o_cur);
    int* csr    = (int*)(ws + o_csr);
    ush* h      = (ush*)(ws + o_h);
    ush* g      = (ush*)(ws + o_g);
    ush* s      = (ush*)(ws + o_s);

    hipMemsetAsync(ws, 0, 256, stream);                          // flags + total
    hipMemsetAsync(cnt, 0, (size_t)n_nodes * 4, stream);

    k_detect<<<1, 256, 0, stream>>>((const unsigned short*)x, ei, flags);
    k_count<<<(n_edges + 255) / 256, 256, 0, stream>>>(ei, n_edges, flags, cnt);
    k_alloc<<<(n_nodes + 255) / 256, 256, 0, stream>>>(cnt, n_nodes, start, cursor, total);
    k_fill<<<(n_edges + 255) / 256, 256, 0, stream>>>(ei, n_edges, flags, cursor, csr);

    k_l1<<<2048, 256, 0, stream>>>(x, start, cnt, csr, W1l, W1r, b1, flags, h, n_nodes, n_edges);
    k_g<<<512, 256, 0, stream>>>(h, W2l, W2r, b2, flags, g, s, n_nodes);
    k_l2g<<<2048, 256, 0, stream>>>(g, s, start, cnt, csr, flags, d_out, n_nodes, n_edges);
}

// Round 12
// 476.851 us; speedup vs baseline: 1.9834x; 1.2477x over previous
//
#include <hip/hip_runtime.h>
#include <hip/hip_bf16.h>

typedef __hip_bfloat16 bf16;
typedef unsigned short ush;
typedef __attribute__((ext_vector_type(8))) unsigned short ush8;
typedef __attribute__((ext_vector_type(4))) float f4;

#define IN_CH 32
#define HID 128
#define OUT_CH 32
#define S_CAP 32             // fixed csr slots per node; rank>=S_CAP -> overflow list
#define OVF_CAP 400000       // overflow pair capacity (bench data: ~0 used)

__device__ __forceinline__ float bf2f(ush u) {
    return __uint_as_float(((unsigned)u) << 16);
}
__device__ __forceinline__ ush f2bf(float f) {
    __hip_bfloat16 b = __float2bfloat16(f);
    return __builtin_bit_cast(ush, b);
}
__device__ __forceinline__ float ldf(const void* __restrict__ p, size_t idx, int isbf16) {
    return isbf16 ? bf2f(((const ush*)p)[idx]) : ((const float*)p)[idx];
}
__device__ __forceinline__ int ld_edge(const int* __restrict__ ei, size_t elem, int wide) {
    return wide ? ei[2 * elem] : ei[elem];
}

// ---------- sniff dtypes: flags[0]=float_is_bf16, flags[1]=edge_is_i64 ----------
__global__ void k_detect(const unsigned short* __restrict__ xraw,
                         const int* __restrict__ ei, int* __restrict__ flags) {
    __shared__ int cnt_exp, any_nz;
    if (threadIdx.x == 0) { cnt_exp = 0; any_nz = 0; }
    __syncthreads();
    int local = 0;
    for (int k = threadIdx.x; k < 4096; k += 256) {
        int e = (xraw[k] >> 7) & 0xFF;
        if (e >= 100 && e <= 140) ++local;
    }
    atomicAdd(&cnt_exp, local);
    for (int k = threadIdx.x; k < 2048; k += 256)
        if (ei[2 * k + 1] != 0) any_nz = 1;   // benign race
    __syncthreads();
    if (threadIdx.x == 0) {
        flags[0] = (cnt_exp > 3500) ? 1 : 0;
        flags[1] = any_nz ? 0 : 1;
    }
}

// ---------- fused count+place: ONE atomic per edge (was 2 across count+fill) ----------
__global__ void k_fillp(const int* __restrict__ ei, int n_edges,
                        const int* __restrict__ flags,
                        int* __restrict__ cnt, int* __restrict__ csr,
                        int* __restrict__ ovf, int* __restrict__ ovfn) {
    int e = blockIdx.x * blockDim.x + threadIdx.x;
    if (e >= n_edges) return;
    int w = flags[1];
    int d  = ld_edge(ei, (size_t)n_edges + e, w);
    int sc = ld_edge(ei, (size_t)e, w);
    int r = atomicAdd(&cnt[d], 1);
    if (r < S_CAP) {
        csr[d * S_CAP + r] = sc;
    } else {
        int o = atomicAdd(ovfn, 1);
        if (o < OVF_CAP) { ((int2*)ovf)[o] = make_int2(d, sc); }
    }
}

// ==== layer 1: h[i] = relu(mean_j x[j] @ W1l^T + x[i] @ W1r^T + b1), 32 -> 128 ====
// wave-per-node; lane = (slot 0..15 = edge slot, chunk 0..3 = 8-channel chunk)
__global__ __launch_bounds__(256) void k_l1(
        const void* __restrict__ x,
        const int* __restrict__ cnt, const int* __restrict__ csr,
        const int* __restrict__ ovf, const int* __restrict__ ovfn,
        const void* __restrict__ W1l, const void* __restrict__ W1r,
        const void* __restrict__ b1,
        const int* __restrict__ flags,
        ush* __restrict__ hout, int n_nodes) {
    __shared__ ush wst[2 * HID * IN_CH];   // 16 KB: W1l then W1r, bf16 [o][c]
    int fb = flags[0];
    int t = threadIdx.x;
    for (int idx = t; idx < HID * IN_CH; idx += 256) {
        wst[idx]                 = f2bf(ldf(W1l, idx, fb));
        wst[HID * IN_CH + idx]   = f2bf(ldf(W1r, idx, fb));
    }
    __syncthreads();
    int wave = t >> 6, lane = t & 63;
    int slot = lane >> 2;    // 0..15
    int chunk = lane & 3;    // 0..3
    ush8 wlr[8], wrr[8];
    float bsr[8];
#pragma unroll
    for (int j = 0; j < 8; ++j) {
        int o = slot * 8 + j;
        wlr[j] = *(const ush8*)&wst[o * IN_CH + chunk * 8];
        wrr[j] = *(const ush8*)&wst[HID * IN_CH + o * IN_CH + chunk * 8];
        bsr[j] = ldf(b1, o, fb);
    }
    int gw = blockIdx.x * 4 + wave;
    int nw = gridDim.x * 4;
    for (int i = gw; i < n_nodes; i += nw) {
        int dg = cnt[i];
        int lim = min(dg, S_CAP);
        int idxv = csr[i * S_CAP + lane];   // lanes >= lim read slack; never used
        float acc[8] = {0, 0, 0, 0, 0, 0, 0, 0};
        float sv[8];
        if (fb) {
            const ush* xb = (const ush*)x;
            for (int g = 0; g < lim; g += 16) {
                int k = g + slot;
                int src = __shfl(idxv, k);
                bool ok = k < lim;
                ush8 v = *(const ush8*)(xb + (size_t)(ok ? src : i) * IN_CH + chunk * 8);
#pragma unroll
                for (int j = 0; j < 8; ++j) acc[j] += ok ? bf2f(v[j]) : 0.0f;
            }
            if (dg > S_CAP) {   // wave-uniform; ~never taken on bench data
                int on = min(*ovfn, OVF_CAP);
                for (int k = 0; k < on; ++k) {
                    int2 pr = ((const int2*)ovf)[k];
                    if (pr.x == i && slot == 0) {
                        ush8 v = *(const ush8*)(xb + (size_t)pr.y * IN_CH + chunk * 8);
#pragma unroll
                        for (int j = 0; j < 8; ++j) acc[j] += bf2f(v[j]);
                    }
                }
            }
            ush8 svv = *(const ush8*)(xb + (size_t)i * IN_CH + chunk * 8);
#pragma unroll
            for (int j = 0; j < 8; ++j) sv[j] = bf2f(svv[j]);
        } else {
            const float* xb = (const float*)x;
            for (int g = 0; g < lim; g += 16) {
                int k = g + slot;
                int src = __shfl(idxv, k);
                bool ok = k < lim;
                const float* rp = xb + (size_t)(ok ? src : i) * IN_CH + chunk * 8;
                f4 a0 = *(const f4*)rp;
                f4 a1 = *(const f4*)(rp + 4);
#pragma unroll
                for (int j = 0; j < 4; ++j) {
                    acc[j]     += ok ? a0[j] : 0.0f;
                    acc[4 + j] += ok ? a1[j] : 0.0f;
                }
            }
            if (dg > S_CAP) {
                int on = min(*ovfn, OVF_CAP);
                for (int k = 0; k < on; ++k) {
                    int2 pr = ((const int2*)ovf)[k];
                    if (pr.x == i && slot == 0) {
                        const float* rp = xb + (size_t)pr.y * IN_CH + chunk * 8;
                        f4 a0 = *(const f4*)rp;
                        f4 a1 = *(const f4*)(rp + 4);
#pragma unroll
                        for (int j = 0; j < 4; ++j) { acc[j] += a0[j]; acc[4 + j] += a1[j]; }
                    }
                }
            }
            const float* rp = xb + (size_t)i * IN_CH + chunk * 8;
            f4 a0 = *(const f4*)rp;
            f4 a1 = *(const f4*)(rp + 4);
#pragma unroll
            for (int j = 0; j < 4; ++j) { sv[j] = a0[j]; sv[4 + j] = a1[j]; }
        }
#pragma unroll
        for (int j = 0; j < 8; ++j) {
            acc[j] += __shfl_xor(acc[j], 4);
            acc[j] += __shfl_xor(acc[j], 8);
            acc[j] += __shfl_xor(acc[j], 16);
            acc[j] += __shfl_xor(acc[j], 32);
        }
        float rdeg = 1.0f / (float)(dg > 1 ? dg : 1);
#pragma unroll
        for (int j = 0; j < 8; ++j) acc[j] *= rdeg;
        float po[8];
#pragma unroll
        for (int j = 0; j < 8; ++j) {
            float s = 0.0f;
#pragma unroll
            for (int c = 0; c < 8; ++c)
                s += acc[c] * bf2f(wlr[j][c]) + sv[c] * bf2f(wrr[j][c]);
            po[j] = s;
        }
#pragma unroll
        for (int j = 0; j < 8; ++j) {
            po[j] += __shfl_xor(po[j], 1);
            po[j] += __shfl_xor(po[j], 2);
        }
        if (chunk == 0) {
            ush8 ov;
#pragma unroll
            for (int j = 0; j < 8; ++j) {
                float v = po[j] + bsr[j];
                ov[j] = f2bf(v > 0.0f ? v : 0.0f);
            }
            *(ush8*)(hout + (size_t)i * HID + slot * 8) = ov;
        }
    }
}

// ==== k_g: in-place into h row — [0..31] <- h@W2l^T, [32..63] <- h@W2r^T+b2 ====
// wave-per-node; lane = (slot 0..3 = 8-output group, chunk 0..15 = 8-ch chunk)
__global__ __launch_bounds__(256) void k_g(
        ush* __restrict__ h,
        const void* __restrict__ W2l, const void* __restrict__ W2r,
        const void* __restrict__ b2,
        const int* __restrict__ flags, int n_nodes) {
    __shared__ ush wst[2 * OUT_CH * HID];  // 16 KB
    int fb = flags[0];
    int t = threadIdx.x;
    for (int idx = t; idx < OUT_CH * HID; idx += 256) {
        wst[idx]                  = f2bf(ldf(W2l, idx, fb));
        wst[OUT_CH * HID + idx]   = f2bf(ldf(W2r, idx, fb));
    }
    __syncthreads();
    int wave = t >> 6, lane = t & 63;
    int slot = lane >> 4;    // 0..3
    int chunk = lane & 15;   // 0..15
    ush8 wlr[8], wrr[8];
    float bsr[8];
#pragma unroll
    for (int j = 0; j < 8; ++j) {
        int o = slot * 8 + j;
        wlr[j] = *(const ush8*)&wst[o * HID + chunk * 8];
        wrr[j] = *(const ush8*)&wst[OUT_CH * HID + o * HID + chunk * 8];
        bsr[j] = ldf(b2, o, fb);
    }
    int gw = blockIdx.x * 4 + wave;
    int nw = gridDim.x * 4;
    for (int i = gw; i < n_nodes; i += nw) {
        ush8 hv = *(const ush8*)(h + (size_t)i * HID + chunk * 8);  // read BEFORE write
        float sv[8];
#pragma unroll
        for (int j = 0; j < 8; ++j) sv[j] = bf2f(hv[j]);
        float pg[8], ps[8];
#pragma unroll
        for (int j = 0; j < 8; ++j) {
            float a = 0.0f, b = 0.0f;
#pragma unroll
            for (int c = 0; c < 8; ++c) {
                a += sv[c] * bf2f(wlr[j][c]);
                b += sv[c] * bf2f(wrr[j][c]);
            }
            pg[j] = a; ps[j] = b;
        }
#pragma unroll
        for (int j = 0; j < 8; ++j) {
            pg[j] += __shfl_xor(pg[j], 1);
            pg[j] += __shfl_xor(pg[j], 2);
            pg[j] += __shfl_xor(pg[j], 4);
            pg[j] += __shfl_xor(pg[j], 8);
            ps[j] += __shfl_xor(ps[j], 1);
            ps[j] += __shfl_xor(ps[j], 2);
            ps[j] += __shfl_xor(ps[j], 4);
            ps[j] += __shfl_xor(ps[j], 8);
        }
        if (chunk == 0) {
            ush8 go, so;
#pragma unroll
            for (int j = 0; j < 8; ++j) {
                go[j] = f2bf(pg[j]);
                so[j] = f2bf(ps[j] + bsr[j]);
            }
            *(ush8*)(h + (size_t)i * HID + slot * 8)      = go;   // g -> [0..31]
            *(ush8*)(h + (size_t)i * HID + 32 + slot * 8) = so;   // s -> [32..63]
        }
    }
}

// ==== out[i] = mean_j g[j] + s[i] — 64B-row gather from h region ====
// wave-per-node; lane = (slot 0..15 = edge slot, chunk 0..3 = 8-channel chunk)
__global__ __launch_bounds__(256) void k_l2g(
        const ush* __restrict__ hg,
        const int* __restrict__ cnt, const int* __restrict__ csr,
        const int* __restrict__ ovf, const int* __restrict__ ovfn,
        const int* __restrict__ flags,
        void* __restrict__ out, int n_nodes) {
    int fb = flags[0];
    int t = threadIdx.x;
    int wave = t >> 6, lane = t & 63;
    int slot = lane >> 2;    // 0..15
    int chunk = lane & 3;    // 0..3
    int gw = blockIdx.x * 4 + wave;
    int nw = gridDim.x * 4;
    for (int i = gw; i < n_nodes; i += nw) {
        int dg = cnt[i];
        int lim = min(dg, S_CAP);
        int idxv = csr[i * S_CAP + lane];
        float acc[8] = {0, 0, 0, 0, 0, 0, 0, 0};
        for (int gg = 0; gg < lim; gg += 16) {
            int k = gg + slot;
            int src = __shfl(idxv, k);
            bool ok = k < lim;
            ush8 v = *(const ush8*)(hg + (size_t)(ok ? src : i) * HID + chunk * 8);
#pragma unroll
            for (int j = 0; j < 8; ++j) acc[j] += ok ? bf2f(v[j]) : 0.0f;
        }
        if (dg > S_CAP) {   // wave-uniform; ~never taken on bench data
            int on = min(*ovfn, OVF_CAP);
            for (int k = 0; k < on; ++k) {
                int2 pr = ((const int2*)ovf)[k];
                if (pr.x == i && slot == 0) {
                    ush8 v = *(const ush8*)(hg + (size_t)pr.y * HID + chunk * 8);
#pragma unroll
                    for (int j = 0; j < 8; ++j) acc[j] += bf2f(v[j]);
                }
            }
        }
#pragma unroll
        for (int j = 0; j < 8; ++j) {
            acc[j] += __shfl_xor(acc[j], 4);
            acc[j] += __shfl_xor(acc[j], 8);
            acc[j] += __shfl_xor(acc[j], 16);
            acc[j] += __shfl_xor(acc[j], 32);
        }
        if (slot == 0) {   // lanes 0..3 hold chunk 0..3
            float rdeg = 1.0f / (float)(dg > 1 ? dg : 1);
            ush8 selfv = *(const ush8*)(hg + (size_t)i * HID + 32 + chunk * 8);
            if (fb) {
                ush8 ov;
#pragma unroll
                for (int j = 0; j < 8; ++j)
                    ov[j] = f2bf(acc[j] * rdeg + bf2f(selfv[j]));
                *(ush8*)((ush*)out + (size_t)i * OUT_CH + chunk * 8) = ov;
            } else {
                float* op = (float*)out + (size_t)i * OUT_CH + chunk * 8;
                f4 a0, a1;
#pragma unroll
                for (int j = 0; j < 4; ++j) {
                    a0[j] = acc[j] * rdeg + bf2f(selfv[j]);
                    a1[j] = acc[4 + j] * rdeg + bf2f(selfv[4 + j]);
                }
                *(f4*)op = a0;
                *(f4*)(op + 4) = a1;
            }
        }
    }
}

extern "C" void kernel_launch(void* const* d_in, const int* in_sizes, int n_in,
                              void* d_out, int out_size, void* d_ws, size_t ws_size,
                              hipStream_t stream) {
    const void* x   = d_in[0];
    const int*  ei  = (const int*)d_in[1];
    const void* W1l = d_in[2];
    const void* W1r = d_in[3];
    const void* b1  = d_in[4];
    const void* W2l = d_in[5];
    const void* W2r = d_in[6];
    const void* b2  = d_in[7];

    int n_nodes = in_sizes[0] / IN_CH;
    int n_edges = in_sizes[1] / 2;

    // ws layout (~42 MB):
    //   [0,256)   flags (2 ints) + ovfn counter (at +128)
    //   cnt (N ints) | csr (N*S_CAP + 64 ints) | ovf (2*OVF_CAP ints)
    //   | h (N*HID bf16; after k_g, row = [g(32) | s(32) | unused])
    char* ws = (char*)d_ws;
    size_t o_cnt = 256;
    size_t o_csr = (o_cnt + (size_t)n_nodes * 4 + 127) & ~(size_t)127;
    size_t o_ovf = (o_csr + ((size_t)n_nodes * S_CAP + 64) * 4 + 127) & ~(size_t)127;
    size_t o_h   = (o_ovf + (size_t)OVF_CAP * 8 + 255) & ~(size_t)255;

    int* flags = (int*)ws;
    int* ovfn  = (int*)(ws + 128);
    int* cnt   = (int*)(ws + o_cnt);
    int* csr   = (int*)(ws + o_csr);
    int* ovf   = (int*)(ws + o_ovf);
    ush* h     = (ush*)(ws + o_h);

    hipMemsetAsync(ws, 0, 256, stream);                          // flags + ovfn
    hipMemsetAsync(cnt, 0, (size_t)n_nodes * 4, stream);

    k_detect<<<1, 256, 0, stream>>>((const unsigned short*)x, ei, flags);
    k_fillp<<<(n_edges + 255) / 256, 256, 0, stream>>>(ei, n_edges, flags, cnt, csr, ovf, ovfn);

    k_l1<<<1024, 256, 0, stream>>>(x, cnt, csr, ovf, ovfn, W1l, W1r, b1, flags, h, n_nodes);
    k_g<<<512, 256, 0, stream>>>(h, W2l, W2r, b2, flags, n_nodes);
    k_l2g<<<1024, 256, 0, stream>>>(h, cnt, csr, ovf, ovfn, flags, d_out, n_nodes);
}